// Round 4
// baseline (3543.599 us; speedup 1.0000x reference)
//
#include <hip/hip_runtime.h>

typedef unsigned int uint;
typedef unsigned short ushort;

#define NNODES 100000
#define MP 100096   // 782 * 128
#define NP 100096
#define NB 32       // column buckets (phase slabs of 3125 cols)
#define RPW 49      // rows per wave in phased aggregation
#define AGG_BLOCKS 1021  // ceil(100000 / (49 rows * 2 waves)) ; 4 blocks/CU resident

typedef __attribute__((ext_vector_type(8))) short bf16x8;
typedef __attribute__((ext_vector_type(4))) float f32x4;

__device__ __forceinline__ float b2f(uint u) {
    union { float f; uint i; } x; x.i = u << 16; return x.f;
}
__device__ __forceinline__ ushort f2b(float f) {
    uint u = __float_as_uint(f);
    u = (u + 0x7fffu + ((u >> 16) & 1u)) >> 16;
    return (ushort)u;
}

// bucket(c) = floor-ish(c / ~3125), consistent everywhere; c < 100000 -> 0..31
__device__ __forceinline__ int colbucket(int c) {
    return (int)(((uint)c * 671u) >> 21);
}

// ---------------- graph preprocessing (bucketed CSR) ----------------
// edge_index arrives as int32: rows = p[0:E], cols = p[E:2E]

__global__ void count_edges2(const int* __restrict__ rows, const int* __restrict__ cols,
                             int* __restrict__ cnt2, int E) {
    int i = blockIdx.x * 256 + threadIdx.x;
    if (i < E) {
        uint r = (uint)rows[i];
        uint c = (uint)cols[i];
        if (r < NNODES && c < NNODES)
            atomicAdd(&cnt2[(size_t)r * NB + colbucket((int)c)], 1);
    }
}

// per-row: deg, dinv, global row_start via wave-scan + one atomic per wave,
// per-bucket prefix -> bb[row][k] = (start, count); cursor2 seeded with start.
__global__ __launch_bounds__(256) void scan_rows(
        const int* __restrict__ cnt2, float* __restrict__ dinv,
        int2* __restrict__ bb, int* __restrict__ cursor2, int* __restrict__ gcur) {
    int row = blockIdx.x * 256 + threadIdx.x;
    int lane = threadIdx.x & 63;
    int c[NB];
    int deg = 0;
    if (row < NNODES) {
#pragma unroll
        for (int k = 0; k < NB; k += 4) {
            int4 v = *(const int4*)&cnt2[(size_t)row * NB + k];
            c[k] = v.x; c[k + 1] = v.y; c[k + 2] = v.z; c[k + 3] = v.w;
            deg += v.x + v.y + v.z + v.w;
        }
        dinv[row] = rsqrtf((float)(deg + 1));
    }
    int incl = deg;
#pragma unroll
    for (int off = 1; off < 64; off <<= 1) {
        int u = __shfl_up(incl, off, 64);
        if (lane >= off) incl += u;
    }
    int base = 0;
    if (lane == 63) base = atomicAdd(gcur, incl);
    base = __shfl(base, 63, 64);
    int p = base + incl - deg;
    if (row < NNODES) {
#pragma unroll
        for (int k = 0; k < NB; ++k) {
            bb[(size_t)row * NB + k] = make_int2(p, c[k]);
            cursor2[(size_t)row * NB + k] = p;
            p += c[k];
        }
    }
}

__global__ void fill_csr2(const int* __restrict__ rows, const int* __restrict__ cols,
                          int* __restrict__ cursor2, int* __restrict__ csr_col, int E) {
    int i = blockIdx.x * 256 + threadIdx.x;
    if (i < E) {
        uint r = (uint)rows[i];
        uint c = (uint)cols[i];
        if (r < NNODES && c < NNODES) {
            int pos = atomicAdd(&cursor2[(size_t)r * NB + colbucket((int)c)], 1);
            csr_col[pos] = (int)c;
        }
    }
}

// ---------------- dtype conversion ----------------

__global__ void convert_x(const float* __restrict__ X, ushort* __restrict__ Xb, int n4) {
    int i = blockIdx.x * 256 + threadIdx.x;
    if (i < n4) {
        float4 v = ((const float4*)X)[i];
        uint2 o;
        o.x = (uint)f2b(v.x) | ((uint)f2b(v.y) << 16);
        o.y = (uint)f2b(v.z) | ((uint)f2b(v.w) << 16);
        ((uint2*)Xb)[i] = o;
    }
}

__global__ void transpose_w(const float* __restrict__ W, ushort* __restrict__ Wt, int K, int Nout) {
    int i = blockIdx.x * 256 + threadIdx.x;
    if (i < K * Nout) {
        int k = i / Nout, n = i % Nout;
        Wt[(size_t)n * K + k] = f2b(W[i]);
    }
}

__global__ void concat_bias(const float* __restrict__ a, const float* __restrict__ b,
                            float* __restrict__ o) {
    int i = threadIdx.x;           // 256 threads
    o[i] = (i < 128) ? a[i] : b[i - 128];
}

// ---------------- GEMM: C = A (Mp x K) * Bt^T (Bt is Nout x K), bf16 MFMA ----------------
// EPI 0: C[m][n] = dinv[m] * acc  -> bf16 Cb
// EPI 1: C[m][n] = acc + bias[n]  -> fp32, split-store

template<int KDIM, int NOUT, int EPI>
__global__ __launch_bounds__(256, 2) void gemm_bt(
        const ushort* __restrict__ A, const ushort* __restrict__ Bt,
        ushort* __restrict__ Cb, float* __restrict__ Cf,
        const float* __restrict__ dinv, const float* __restrict__ bias, int Mvalid) {
    __shared__ __align__(16) ushort Alds[128][72];
    __shared__ __align__(16) ushort Blds[128][72];
    __shared__ float dlds[128];

    const int tid = threadIdx.x;
    const int bm0 = blockIdx.x * 128;
    const int bn0 = blockIdx.y * 128;
    const int w = tid >> 6, lane = tid & 63;
    const int wm = (w >> 1) * 64, wn = (w & 1) * 64;
    const int lm = lane & 15, lq = lane >> 4;

    f32x4 acc[4][4] = {};
    if (EPI == 0 && tid < 128) dlds[tid] = dinv[bm0 + tid];

    const int sr = tid >> 3;        // 0..31
    const int sc = (tid & 7) * 8;   // bf16 col 0..56

    for (int k0 = 0; k0 < KDIM; k0 += 64) {
        uint4 ar[4], br[4];
#pragma unroll
        for (int i = 0; i < 4; ++i) {
            int r = sr + i * 32;
            ar[i] = *(const uint4*)&A[(size_t)(bm0 + r) * KDIM + k0 + sc];
            br[i] = *(const uint4*)&Bt[(size_t)(bn0 + r) * KDIM + k0 + sc];
        }
        __syncthreads();
#pragma unroll
        for (int i = 0; i < 4; ++i) {
            int r = sr + i * 32;
            *(uint4*)&Alds[r][sc] = ar[i];
            *(uint4*)&Blds[r][sc] = br[i];
        }
        __syncthreads();
#pragma unroll
        for (int kk = 0; kk < 64; kk += 32) {
            bf16x8 af[4], bfr[4];
#pragma unroll
            for (int t = 0; t < 4; ++t) af[t]  = *(const bf16x8*)&Alds[wm + t * 16 + lm][kk + lq * 8];
#pragma unroll
            for (int t = 0; t < 4; ++t) bfr[t] = *(const bf16x8*)&Blds[wn + t * 16 + lm][kk + lq * 8];
#pragma unroll
            for (int tm = 0; tm < 4; ++tm)
#pragma unroll
                for (int tn = 0; tn < 4; ++tn)
                    acc[tm][tn] = __builtin_amdgcn_mfma_f32_16x16x32_bf16(
                        af[tm], bfr[tn], acc[tm][tn], 0, 0, 0);
        }
    }

    // epilogue: C/D layout col = lane&15, row = (lane>>4)*4 + reg  [m89/m91]
#pragma unroll
    for (int tm = 0; tm < 4; ++tm) {
#pragma unroll
        for (int tn = 0; tn < 4; ++tn) {
#pragma unroll
            for (int r = 0; r < 4; ++r) {
                int lr = wm + tm * 16 + lq * 4 + r;
                int gr = bm0 + lr;
                int gc = bn0 + wn + tn * 16 + lm;
                float v = acc[tm][tn][r];
                if (EPI == 0) {
                    v *= dlds[lr];
                    Cb[(size_t)gr * NOUT + gc] = f2b(v);
                } else {
                    v += bias[gc];
                    if (gr < Mvalid) {
                        size_t off = (gc < 128)
                            ? ((size_t)gr * 128 + gc)
                            : ((size_t)NNODES * 128 + (size_t)gr * 128 + (gc - 128));
                        Cf[off] = v;
                    }
                }
            }
        }
    }
}

// ---------------- phased aggregation ----------------
// out[r] = act(dinv[r]*(sum_{c in N(r)} xw'[c] + xw'[r]) + b)   (xw' rows pre-scaled by dinv)
//
// One resident generation of waves (1021 blocks x 128thr = 4 blocks/CU at <=256 VGPR).
// Each wave owns RPW=49 consecutive rows, accumulators in registers (f32).
// All waves sweep NB=32 column buckets in the same order: at any instant the gather
// working set is ~1-2 slabs (1.6-3.2 MB) -> per-XCD L2 resident.
// Per phase: branchless pass A (edge 0), pass B (edge 1), rare pass C (edges 2+).
// First/second cols prefetched lane-parallel one phase ahead; inactive sections gather
// a masked dummy slab row (hot line, FMA*0).

template<int F>
__device__ __forceinline__ void gadd(const ushort* __restrict__ tb, int c, float* a) {
    if constexpr (F == 256) {
        uint2 v = *(const uint2*)(tb + (size_t)c * 256);
        a[0] += b2f(v.x & 0xffffu); a[1] += b2f(v.x >> 16);
        a[2] += b2f(v.y & 0xffffu); a[3] += b2f(v.y >> 16);
    } else {
        uint v = *(const uint*)(tb + (size_t)c * 128);
        a[0] += b2f(v & 0xffffu); a[1] += b2f(v >> 16);
    }
}

template<int F>
__device__ __forceinline__ void gmask(const ushort* __restrict__ tb, int c, float m, float* a) {
    if constexpr (F == 256) {
        uint2 v = *(const uint2*)(tb + (size_t)c * 256);
        a[0] = fmaf(m, b2f(v.x & 0xffffu), a[0]);
        a[1] = fmaf(m, b2f(v.x >> 16),     a[1]);
        a[2] = fmaf(m, b2f(v.y & 0xffffu), a[2]);
        a[3] = fmaf(m, b2f(v.y >> 16),     a[3]);
    } else {
        uint v = *(const uint*)(tb + (size_t)c * 128);
        a[0] = fmaf(m, b2f(v & 0xffffu), a[0]);
        a[1] = fmaf(m, b2f(v >> 16),     a[1]);
    }
}

template<int F, bool RELU>
__global__ __launch_bounds__(128, 2) void agg_phased(
        const ushort* __restrict__ xw, const int* __restrict__ csr,
        const int2* __restrict__ bb, const float* __restrict__ dinv,
        const float* __restrict__ bias, ushort* __restrict__ out, int E) {
    constexpr int PF = F / 64;               // f32 accum per lane per row
    const int lane = threadIdx.x & 63;
    const int wv = blockIdx.x * 2 + (threadIdx.x >> 6);
    const int row0 = wv * RPW;
    const int myrow = row0 + lane;
    const bool rv = (lane < RPW) && (myrow < NNODES);
    const float dvl = rv ? dinv[myrow] : 0.f;
    const int Emax = E - 1;
    const ushort* tb = xw + lane * PF;       // per-lane feature slice base

    float a[RPW][PF];
#pragma unroll
    for (int r = 0; r < RPW; ++r)
#pragma unroll
        for (int k = 0; k < PF; ++k) a[r][k] = 0.f;

    // self contributions (phase-independent; row0+r < MP always so loads are safe;
    // garbage rows >= NNODES only pollute accumulators that are never stored)
#pragma unroll
    for (int r = 0; r < RPW; ++r) gadd<F>(tb, row0 + r, a[r]);

    // phase-0 metadata + first/second column prefetch (lane l holds row row0+l's bucket)
    int2 sn = rv ? bb[(size_t)myrow * NB + 0] : make_int2(0, 0);
    int i0 = (sn.x < Emax) ? sn.x : Emax;
    int i1 = (sn.x + 1 < Emax) ? sn.x + 1 : Emax;
    int c0v = csr[i0];
    int c1v = csr[i1];

    for (int b = 0; b < NB; ++b) {
        const int bn = (b + 1 < NB) ? b + 1 : b;
        int2 snn = rv ? bb[(size_t)myrow * NB + bn] : make_int2(0, 0);
        const int dummyc = b * 3125;         // hot in-slab row; finite; < NNODES

        // pass A: first edge of each bucket (branchless straight-line)
#pragma unroll
        for (int r = 0; r < RPW; ++r) {
            int n = __shfl(sn.y, r, 64);
            int cc = __shfl(c0v, r, 64);
            float m = (n >= 1) ? 1.f : 0.f;
            cc = (n >= 1) ? cc : dummyc;
            gmask<F>(tb, cc, m, a[r]);
        }

        // next-phase column prefetch (overlaps with pass B)
        int j0 = (snn.x < Emax) ? snn.x : Emax;
        int j1 = (snn.x + 1 < Emax) ? snn.x + 1 : Emax;
        int c0n = csr[j0];
        int c1n = csr[j1];

        // pass B: second edge (branchless)
#pragma unroll
        for (int r = 0; r < RPW; ++r) {
            int n = __shfl(sn.y, r, 64);
            int cc = __shfl(c1v, r, 64);
            float m = (n >= 2) ? 1.f : 0.f;
            cc = (n >= 2) ? cc : dummyc;
            gmask<F>(tb, cc, m, a[r]);
        }

        // pass C: remaining edges (P(n>=3) ~ 8%, csr line already warm)
#pragma unroll
        for (int r = 0; r < RPW; ++r) {
            int n = __shfl(sn.y, r, 64);
            if (n >= 3) {
                int s = __shfl(sn.x, r, 64);
                int e = s + n;
                for (int i = s + 2; i < e; ++i) gadd<F>(tb, csr[i], a[r]);
            }
        }

        sn = snn; c0v = c0n; c1v = c1n;
        __syncthreads();                     // keep the block's 2 waves phase-aligned
    }

    // epilogue: scale by dinv[row], add bias, optional relu, bf16 store
    // (plain stores: z1/z2 are re-read by the next GEMM/aggregation, keep cached)
    if constexpr (F == 256) {
        float4 bv = *(const float4*)&bias[lane * 4];
#pragma unroll
        for (int r = 0; r < RPW; ++r) {
            int row = row0 + r;
            if (row < NNODES) {
                float d = __shfl(dvl, r, 64);
                float r0 = a[r][0] * d + bv.x;
                float r1 = a[r][1] * d + bv.y;
                float r2 = a[r][2] * d + bv.z;
                float r3 = a[r][3] * d + bv.w;
                if (RELU) {
                    r0 = fmaxf(r0, 0.f); r1 = fmaxf(r1, 0.f);
                    r2 = fmaxf(r2, 0.f); r3 = fmaxf(r3, 0.f);
                }
                uint2 o;
                o.x = (uint)f2b(r0) | ((uint)f2b(r1) << 16);
                o.y = (uint)f2b(r2) | ((uint)f2b(r3) << 16);
                *(uint2*)(out + (size_t)row * 256 + lane * 4) = o;
            }
        }
    } else {
        float2 bv = *(const float2*)&bias[lane * 2];
#pragma unroll
        for (int r = 0; r < RPW; ++r) {
            int row = row0 + r;
            if (row < NNODES) {
                float d = __shfl(dvl, r, 64);
                float r0 = a[r][0] * d + bv.x;
                float r1 = a[r][1] * d + bv.y;
                if (RELU) { r0 = fmaxf(r0, 0.f); r1 = fmaxf(r1, 0.f); }
                *(uint*)(out + (size_t)row * 128 + lane * 2) =
                    (uint)f2b(r0) | ((uint)f2b(r1) << 16);
            }
        }
    }
}

// ---------------- launch ----------------

extern "C" void kernel_launch(void* const* d_in, const int* in_sizes, int n_in,
                              void* d_out, int out_size, void* d_ws, size_t ws_size,
                              hipStream_t stream) {
    (void)n_in; (void)out_size; (void)ws_size;
    const float* x   = (const float*)d_in[0];
    const int*   ei  = (const int*)d_in[1];   // int64 in reference -> int32 from harness
    const float* W1  = (const float*)d_in[2];
    const float* b1  = (const float*)d_in[3];
    const float* W2  = (const float*)d_in[4];
    const float* b2  = (const float*)d_in[5];
    const float* Wmu = (const float*)d_in[6];
    const float* bmu = (const float*)d_in[7];
    const float* Wlv = (const float*)d_in[8];
    const float* blv = (const float*)d_in[9];
    float* out = (float*)d_out;

    const int E = in_sizes[1] / 2;
    const int* rows = ei;
    const int* cols = ei + E;

    char* ws = (char*)d_ws;
    size_t o = 0;
    int2*  bb   = (int2*)(ws + o);  o += (size_t)NNODES * NB * sizeof(int2);  // 25.6 MB
    float* dinv = (float*)(ws + o); o += (size_t)NP * 4;
    int*   gcur = (int*)(ws + o);   o += 256;
    float* bcat = (float*)(ws + o); o += 1024;
    ushort* W1t = (ushort*)(ws + o); o += 256 * 256 * 2;
    ushort* W2t = (ushort*)(ws + o); o += 256 * 128 * 2;
    ushort* Wht = (ushort*)(ws + o); o += 256 * 128 * 2;  // [Wmu^T ; Wlv^T]
    int*   csr  = (int*)(ws + o);   o += (size_t)E * 4;
    o = (o + 4095) & ~(size_t)4095;
    ushort* bufA = (ushort*)(ws + o); o += (size_t)MP * 256 * 2;
    ushort* bufB = (ushort*)(ws + o); o += (size_t)MP * 256 * 2;

    // cnt2/cursor2 alias the head of bufB: dead before gemm1 writes xw1 there.
    int* cnt2    = (int*)bufB;
    int* cursor2 = (int*)((char*)bufB + (size_t)NNODES * NB * 4);

    // buffer lifetimes: bufA = xb -> z1 -> z2 ; bufB = (cnt2|cursor2) -> xw1 -> xw2
    ushort* xb  = bufA;
    ushort* xw1 = bufB;
    ushort* z1  = bufA;
    ushort* xw2 = bufB;
    ushort* z2  = bufA;

    (void)hipMemsetAsync(cnt2, 0, (size_t)NNODES * NB * 4, stream);
    (void)hipMemsetAsync(gcur, 0, 4, stream);

    count_edges2<<<dim3((E + 255) / 256), 256, 0, stream>>>(rows, cols, cnt2, E);
    scan_rows<<<dim3((NNODES + 255) / 256), 256, 0, stream>>>(cnt2, dinv, bb, cursor2, gcur);
    fill_csr2<<<dim3((E + 255) / 256), 256, 0, stream>>>(rows, cols, cursor2, csr, E);

    convert_x<<<dim3((NNODES * 256 / 4 + 255) / 256), 256, 0, stream>>>(x, xb, NNODES * 256 / 4);
    transpose_w<<<dim3((256 * 256 + 255) / 256), 256, 0, stream>>>(W1, W1t, 256, 256);
    transpose_w<<<dim3((256 * 128 + 255) / 256), 256, 0, stream>>>(W2, W2t, 256, 128);
    transpose_w<<<dim3((128 * 128 + 255) / 256), 256, 0, stream>>>(Wmu, Wht, 128, 128);
    transpose_w<<<dim3((128 * 128 + 255) / 256), 256, 0, stream>>>(Wlv, Wht + 128 * 128, 128, 128);
    concat_bias<<<1, 256, 0, stream>>>(bmu, blv, bcat);

    // conv1: xw1' = dinv .* (x @ W1)   [bf16]
    gemm_bt<256, 256, 0><<<dim3(MP / 128, 2), 256, 0, stream>>>(xb, W1t, xw1, nullptr, dinv, nullptr, MP);
    agg_phased<256, true><<<dim3(AGG_BLOCKS), 128, 0, stream>>>(xw1, csr, bb, dinv, b1, z1, E);

    // conv2: xw2' = dinv .* (z1 @ W2)  [bf16]
    gemm_bt<256, 128, 0><<<dim3(MP / 128, 1), 256, 0, stream>>>(z1, W2t, xw2, nullptr, dinv, nullptr, MP);
    agg_phased<128, false><<<dim3(AGG_BLOCKS), 128, 0, stream>>>(xw2, csr, bb, dinv, b2, z2, E);

    // fused heads: [mu | logvar] = z2 @ [Wmu Wlv] + [bmu blv], split-stored
    gemm_bt<128, 256, 1><<<dim3(MP / 128, 2), 256, 0, stream>>>(z2, Wht, nullptr, out, dinv, bcat, NNODES);
}

// Round 5
// 3490.143 us; speedup vs baseline: 1.0153x; 1.0153x over previous
//
#include <hip/hip_runtime.h>

typedef unsigned int uint;
typedef unsigned short ushort;

#define NNODES 100000
#define MP 100096   // 782 * 128
#define NP 100096
#define NB 32       // column buckets (phase slabs of 3125 cols)
#define RPW 49      // rows per wave in phased aggregation
#define AGG_BLOCKS 1021  // ceil(100000 / (49 rows * 2 waves)) ; 4 blocks/CU resident

typedef __attribute__((ext_vector_type(8))) short bf16x8;
typedef __attribute__((ext_vector_type(4))) float f32x4;
typedef __attribute__((ext_vector_type(2))) float f32x2;

__device__ __forceinline__ float b2f(uint u) {
    union { float f; uint i; } x; x.i = u << 16; return x.f;
}
__device__ __forceinline__ ushort f2b(float f) {
    uint u = __float_as_uint(f);
    u = (u + 0x7fffu + ((u >> 16) & 1u)) >> 16;
    return (ushort)u;
}

// bucket(c) = floor-ish(c / ~3125), consistent everywhere; c < 100000 -> 0..31
__device__ __forceinline__ int colbucket(int c) {
    return (int)(((uint)c * 671u) >> 21);
}

// ---------------- graph preprocessing (bucketed CSR) ----------------
// edge_index arrives as int32: rows = p[0:E], cols = p[E:2E]

__global__ void count_edges2(const int* __restrict__ rows, const int* __restrict__ cols,
                             int* __restrict__ cnt2, int E) {
    int i = blockIdx.x * 256 + threadIdx.x;
    if (i < E) {
        uint r = (uint)rows[i];
        uint c = (uint)cols[i];
        if (r < NNODES && c < NNODES)
            atomicAdd(&cnt2[(size_t)r * NB + colbucket((int)c)], 1);
    }
}

// per-row: deg, dinv, global row_start via wave-scan + one atomic per wave,
// per-bucket prefix -> bb[row][k] = (start, count); cursor2 seeded with start.
__global__ __launch_bounds__(256) void scan_rows(
        const int* __restrict__ cnt2, float* __restrict__ dinv,
        int2* __restrict__ bb, int* __restrict__ cursor2, int* __restrict__ gcur) {
    int row = blockIdx.x * 256 + threadIdx.x;
    int lane = threadIdx.x & 63;
    int c[NB];
    int deg = 0;
    if (row < NNODES) {
#pragma unroll
        for (int k = 0; k < NB; k += 4) {
            int4 v = *(const int4*)&cnt2[(size_t)row * NB + k];
            c[k] = v.x; c[k + 1] = v.y; c[k + 2] = v.z; c[k + 3] = v.w;
            deg += v.x + v.y + v.z + v.w;
        }
        dinv[row] = rsqrtf((float)(deg + 1));
    }
    int incl = deg;
#pragma unroll
    for (int off = 1; off < 64; off <<= 1) {
        int u = __shfl_up(incl, off, 64);
        if (lane >= off) incl += u;
    }
    int base = 0;
    if (lane == 63) base = atomicAdd(gcur, incl);
    base = __shfl(base, 63, 64);
    int p = base + incl - deg;
    if (row < NNODES) {
#pragma unroll
        for (int k = 0; k < NB; ++k) {
            bb[(size_t)row * NB + k] = make_int2(p, c[k]);
            cursor2[(size_t)row * NB + k] = p;
            p += c[k];
        }
    }
}

__global__ void fill_csr2(const int* __restrict__ rows, const int* __restrict__ cols,
                          int* __restrict__ cursor2, int* __restrict__ csr_col, int E) {
    int i = blockIdx.x * 256 + threadIdx.x;
    if (i < E) {
        uint r = (uint)rows[i];
        uint c = (uint)cols[i];
        if (r < NNODES && c < NNODES) {
            int pos = atomicAdd(&cursor2[(size_t)r * NB + colbucket((int)c)], 1);
            csr_col[pos] = (int)c;
        }
    }
}

// ---------------- dtype conversion ----------------

__global__ void convert_x(const float* __restrict__ X, ushort* __restrict__ Xb, int n4) {
    int i = blockIdx.x * 256 + threadIdx.x;
    if (i < n4) {
        float4 v = ((const float4*)X)[i];
        uint2 o;
        o.x = (uint)f2b(v.x) | ((uint)f2b(v.y) << 16);
        o.y = (uint)f2b(v.z) | ((uint)f2b(v.w) << 16);
        ((uint2*)Xb)[i] = o;
    }
}

__global__ void transpose_w(const float* __restrict__ W, ushort* __restrict__ Wt, int K, int Nout) {
    int i = blockIdx.x * 256 + threadIdx.x;
    if (i < K * Nout) {
        int k = i / Nout, n = i % Nout;
        Wt[(size_t)n * K + k] = f2b(W[i]);
    }
}

__global__ void concat_bias(const float* __restrict__ a, const float* __restrict__ b,
                            float* __restrict__ o) {
    int i = threadIdx.x;           // 256 threads
    o[i] = (i < 128) ? a[i] : b[i - 128];
}

// ---------------- GEMM: C = A (Mp x K) * Bt^T (Bt is Nout x K), bf16 MFMA ----------------
// EPI 0: C[m][n] = dinv[m] * acc  -> bf16 Cb
// EPI 1: C[m][n] = acc + bias[n]  -> fp32, split-store

template<int KDIM, int NOUT, int EPI>
__global__ __launch_bounds__(256, 2) void gemm_bt(
        const ushort* __restrict__ A, const ushort* __restrict__ Bt,
        ushort* __restrict__ Cb, float* __restrict__ Cf,
        const float* __restrict__ dinv, const float* __restrict__ bias, int Mvalid) {
    __shared__ __align__(16) ushort Alds[128][72];
    __shared__ __align__(16) ushort Blds[128][72];
    __shared__ float dlds[128];

    const int tid = threadIdx.x;
    const int bm0 = blockIdx.x * 128;
    const int bn0 = blockIdx.y * 128;
    const int w = tid >> 6, lane = tid & 63;
    const int wm = (w >> 1) * 64, wn = (w & 1) * 64;
    const int lm = lane & 15, lq = lane >> 4;

    f32x4 acc[4][4] = {};
    if (EPI == 0 && tid < 128) dlds[tid] = dinv[bm0 + tid];

    const int sr = tid >> 3;        // 0..31
    const int sc = (tid & 7) * 8;   // bf16 col 0..56

    for (int k0 = 0; k0 < KDIM; k0 += 64) {
        uint4 ar[4], br[4];
#pragma unroll
        for (int i = 0; i < 4; ++i) {
            int r = sr + i * 32;
            ar[i] = *(const uint4*)&A[(size_t)(bm0 + r) * KDIM + k0 + sc];
            br[i] = *(const uint4*)&Bt[(size_t)(bn0 + r) * KDIM + k0 + sc];
        }
        __syncthreads();
#pragma unroll
        for (int i = 0; i < 4; ++i) {
            int r = sr + i * 32;
            *(uint4*)&Alds[r][sc] = ar[i];
            *(uint4*)&Blds[r][sc] = br[i];
        }
        __syncthreads();
#pragma unroll
        for (int kk = 0; kk < 64; kk += 32) {
            bf16x8 af[4], bfr[4];
#pragma unroll
            for (int t = 0; t < 4; ++t) af[t]  = *(const bf16x8*)&Alds[wm + t * 16 + lm][kk + lq * 8];
#pragma unroll
            for (int t = 0; t < 4; ++t) bfr[t] = *(const bf16x8*)&Blds[wn + t * 16 + lm][kk + lq * 8];
#pragma unroll
            for (int tm = 0; tm < 4; ++tm)
#pragma unroll
                for (int tn = 0; tn < 4; ++tn)
                    acc[tm][tn] = __builtin_amdgcn_mfma_f32_16x16x32_bf16(
                        af[tm], bfr[tn], acc[tm][tn], 0, 0, 0);
        }
    }

    // epilogue: C/D layout col = lane&15, row = (lane>>4)*4 + reg  [m89/m91]
#pragma unroll
    for (int tm = 0; tm < 4; ++tm) {
#pragma unroll
        for (int tn = 0; tn < 4; ++tn) {
#pragma unroll
            for (int r = 0; r < 4; ++r) {
                int lr = wm + tm * 16 + lq * 4 + r;
                int gr = bm0 + lr;
                int gc = bn0 + wn + tn * 16 + lm;
                float v = acc[tm][tn][r];
                if (EPI == 0) {
                    v *= dlds[lr];
                    Cb[(size_t)gr * NOUT + gc] = f2b(v);
                } else {
                    v += bias[gc];
                    if (gr < Mvalid) {
                        size_t off = (gc < 128)
                            ? ((size_t)gr * 128 + gc)
                            : ((size_t)NNODES * 128 + (size_t)gr * 128 + (gc - 128));
                        Cf[off] = v;
                    }
                }
            }
        }
    }
}

// ---------------- phased aggregation ----------------
// out[r] = act(dinv[r]*(sum_{c in N(r)} xw'[c] + xw'[r]) + b)   (xw' rows pre-scaled by dinv)
//
// One resident generation of waves (1021 blocks x 128thr = 4 blocks/CU at <=256 VGPR).
// Each wave owns RPW=49 consecutive rows; accumulators are 49 NAMED vector registers
// (macro-expanded, not an array -> no SROA failure -> no scratch; R4 post-mortem:
// float a[49][4] went to scratch, 3.3 GB of spill writes, 9x slowdown).
// All waves sweep NB=32 column buckets in the same order: at any instant the gather
// working set is ~1-2 slabs (1.6-3.2 MB) -> per-XCD L2 resident.
// Per phase: branchless pass A (edge 0), pass B (edge 1), rare pass C (edges 2+).
// First/second cols prefetched lane-parallel one phase ahead; inactive sections gather
// a masked dummy slab row (hot line, FMA*0).

template<int F> struct accsel;
template<> struct accsel<256> { typedef f32x4 T; };
template<> struct accsel<128> { typedef f32x2 T; };

__device__ __forceinline__ void gacc4(const ushort* __restrict__ tb, int c, float m, f32x4& a) {
    uint2 v = *(const uint2*)(tb + (size_t)c * 256);
    a[0] = fmaf(m, b2f(v.x & 0xffffu), a[0]);
    a[1] = fmaf(m, b2f(v.x >> 16),     a[1]);
    a[2] = fmaf(m, b2f(v.y & 0xffffu), a[2]);
    a[3] = fmaf(m, b2f(v.y >> 16),     a[3]);
}
__device__ __forceinline__ void gacc2(const ushort* __restrict__ tb, int c, float m, f32x2& a) {
    uint v = *(const uint*)(tb + (size_t)c * 128);
    a[0] = fmaf(m, b2f(v & 0xffffu), a[0]);
    a[1] = fmaf(m, b2f(v >> 16),     a[1]);
}

#define ROWS49(X) \
    X(0) X(1) X(2) X(3) X(4) X(5) X(6) X(7) X(8) X(9) \
    X(10) X(11) X(12) X(13) X(14) X(15) X(16) X(17) X(18) X(19) \
    X(20) X(21) X(22) X(23) X(24) X(25) X(26) X(27) X(28) X(29) \
    X(30) X(31) X(32) X(33) X(34) X(35) X(36) X(37) X(38) X(39) \
    X(40) X(41) X(42) X(43) X(44) X(45) X(46) X(47) X(48)

template<int F, bool RELU>
__global__ __launch_bounds__(128, 2) void agg_phased(
        const ushort* __restrict__ xw, const int* __restrict__ csr,
        const int2* __restrict__ bb, const float* __restrict__ dinv,
        const float* __restrict__ bias, ushort* __restrict__ out, int E) {
    constexpr int PF = F / 64;               // f32 accum per lane per row
    using AccT = typename accsel<F>::T;
    const int lane = threadIdx.x & 63;
    const int wv = blockIdx.x * 2 + (threadIdx.x >> 6);
    const int row0 = wv * RPW;
    const int myrow = row0 + lane;
    const bool rv = (lane < RPW) && (myrow < NNODES);
    const float dvl = rv ? dinv[myrow] : 0.f;
    const int Emax = E - 1;
    const ushort* tb = xw + lane * PF;       // per-lane feature slice base

#define GACC(cc, m, ar) do { if constexpr (F == 256) gacc4(tb, (cc), (m), ar); \
                             else gacc2(tb, (cc), (m), ar); } while (0)

    // 49 named accumulators (registers by construction)
#define DECLA(r) AccT a##r = {};
    ROWS49(DECLA)
#undef DECLA

    // self contributions (phase-independent; row0+r < MP always so loads are safe;
    // garbage rows >= NNODES only pollute accumulators that are never stored)
#define SELFA(r) GACC(row0 + r, 1.f, a##r);
    ROWS49(SELFA)
#undef SELFA

    // phase-0 metadata + first/second column prefetch (lane l holds row row0+l's bucket)
    int2 sn = rv ? bb[(size_t)myrow * NB + 0] : make_int2(0, 0);
    int i0 = (sn.x < Emax) ? sn.x : Emax;
    int i1 = (sn.x + 1 < Emax) ? sn.x + 1 : Emax;
    int c0v = csr[i0];
    int c1v = csr[i1];

    for (int b = 0; b < NB; ++b) {
        const int bn = (b + 1 < NB) ? b + 1 : b;
        int2 snn = rv ? bb[(size_t)myrow * NB + bn] : make_int2(0, 0);
        const int dummyc = b * 3125;         // hot in-slab row; finite; < NNODES

        // pass A: first edge of each bucket (branchless straight-line)
#define PASSA(r) { int n = __shfl(sn.y, r, 64); int cc = __shfl(c0v, r, 64); \
                   float m = (n >= 1) ? 1.f : 0.f; cc = (n >= 1) ? cc : dummyc; \
                   GACC(cc, m, a##r); }
        ROWS49(PASSA)
#undef PASSA

        // next-phase column prefetch (overlaps with pass B)
        int j0 = (snn.x < Emax) ? snn.x : Emax;
        int j1 = (snn.x + 1 < Emax) ? snn.x + 1 : Emax;
        int c0n = csr[j0];
        int c1n = csr[j1];

        // pass B: second edge (branchless)
#define PASSB(r) { int n = __shfl(sn.y, r, 64); int cc = __shfl(c1v, r, 64); \
                   float m = (n >= 2) ? 1.f : 0.f; cc = (n >= 2) ? cc : dummyc; \
                   GACC(cc, m, a##r); }
        ROWS49(PASSB)
#undef PASSB

        // pass C: remaining edges (P(n>=3) ~ 8%, csr line already warm)
#define PASSC(r) { int n = __shfl(sn.y, r, 64); \
                   if (n >= 3) { int s = __shfl(sn.x, r, 64); int e = s + n; \
                                 for (int i = s + 2; i < e; ++i) GACC(csr[i], 1.f, a##r); } }
        ROWS49(PASSC)
#undef PASSC

        sn = snn; c0v = c0n; c1v = c1n;
        __syncthreads();                     // keep the block's 2 waves phase-aligned
    }

    // epilogue: scale by dinv[row], add bias, optional relu, bf16 store
    // (plain stores: z1/z2 are re-read by the next GEMM/aggregation, keep cached)
    float bb0 = 0.f, bb1 = 0.f, bb2 = 0.f, bb3 = 0.f;
    if constexpr (F == 256) {
        float4 t = *(const float4*)&bias[lane * 4];
        bb0 = t.x; bb1 = t.y; bb2 = t.z; bb3 = t.w;
    } else {
        float2 t = *(const float2*)&bias[lane * 2];
        bb0 = t.x; bb1 = t.y;
    }
#define EPIL(r) { int row = row0 + r; \
    if (row < NNODES) { \
        float d = __shfl(dvl, r, 64); \
        if constexpr (F == 256) { \
            float r0 = a##r[0] * d + bb0; \
            float r1 = a##r[1] * d + bb1; \
            float r2 = a##r[2] * d + bb2; \
            float r3 = a##r[3] * d + bb3; \
            if (RELU) { r0 = fmaxf(r0, 0.f); r1 = fmaxf(r1, 0.f); \
                        r2 = fmaxf(r2, 0.f); r3 = fmaxf(r3, 0.f); } \
            uint2 o; \
            o.x = (uint)f2b(r0) | ((uint)f2b(r1) << 16); \
            o.y = (uint)f2b(r2) | ((uint)f2b(r3) << 16); \
            *(uint2*)(out + (size_t)row * 256 + lane * 4) = o; \
        } else { \
            float r0 = a##r[0] * d + bb0; \
            float r1 = a##r[1] * d + bb1; \
            if (RELU) { r0 = fmaxf(r0, 0.f); r1 = fmaxf(r1, 0.f); } \
            *(uint*)(out + (size_t)row * 128 + lane * 2) = \
                (uint)f2b(r0) | ((uint)f2b(r1) << 16); \
        } } }
    ROWS49(EPIL)
#undef EPIL
#undef GACC
}

// ---------------- launch ----------------

extern "C" void kernel_launch(void* const* d_in, const int* in_sizes, int n_in,
                              void* d_out, int out_size, void* d_ws, size_t ws_size,
                              hipStream_t stream) {
    (void)n_in; (void)out_size; (void)ws_size;
    const float* x   = (const float*)d_in[0];
    const int*   ei  = (const int*)d_in[1];   // int64 in reference -> int32 from harness
    const float* W1  = (const float*)d_in[2];
    const float* b1  = (const float*)d_in[3];
    const float* W2  = (const float*)d_in[4];
    const float* b2  = (const float*)d_in[5];
    const float* Wmu = (const float*)d_in[6];
    const float* bmu = (const float*)d_in[7];
    const float* Wlv = (const float*)d_in[8];
    const float* blv = (const float*)d_in[9];
    float* out = (float*)d_out;

    const int E = in_sizes[1] / 2;
    const int* rows = ei;
    const int* cols = ei + E;

    char* ws = (char*)d_ws;
    size_t o = 0;
    int2*  bb   = (int2*)(ws + o);  o += (size_t)NNODES * NB * sizeof(int2);  // 25.6 MB
    float* dinv = (float*)(ws + o); o += (size_t)NP * 4;
    int*   gcur = (int*)(ws + o);   o += 256;
    float* bcat = (float*)(ws + o); o += 1024;
    ushort* W1t = (ushort*)(ws + o); o += 256 * 256 * 2;
    ushort* W2t = (ushort*)(ws + o); o += 256 * 128 * 2;
    ushort* Wht = (ushort*)(ws + o); o += 256 * 128 * 2;  // [Wmu^T ; Wlv^T]
    int*   csr  = (int*)(ws + o);   o += (size_t)E * 4;
    o = (o + 4095) & ~(size_t)4095;
    ushort* bufA = (ushort*)(ws + o); o += (size_t)MP * 256 * 2;
    ushort* bufB = (ushort*)(ws + o); o += (size_t)MP * 256 * 2;

    // cnt2/cursor2 alias the head of bufB: dead before gemm1 writes xw1 there.
    int* cnt2    = (int*)bufB;
    int* cursor2 = (int*)((char*)bufB + (size_t)NNODES * NB * 4);

    // buffer lifetimes: bufA = xb -> z1 -> z2 ; bufB = (cnt2|cursor2) -> xw1 -> xw2
    ushort* xb  = bufA;
    ushort* xw1 = bufB;
    ushort* z1  = bufA;
    ushort* xw2 = bufB;
    ushort* z2  = bufA;

    (void)hipMemsetAsync(cnt2, 0, (size_t)NNODES * NB * 4, stream);
    (void)hipMemsetAsync(gcur, 0, 4, stream);

    count_edges2<<<dim3((E + 255) / 256), 256, 0, stream>>>(rows, cols, cnt2, E);
    scan_rows<<<dim3((NNODES + 255) / 256), 256, 0, stream>>>(cnt2, dinv, bb, cursor2, gcur);
    fill_csr2<<<dim3((E + 255) / 256), 256, 0, stream>>>(rows, cols, cursor2, csr, E);

    convert_x<<<dim3((NNODES * 256 / 4 + 255) / 256), 256, 0, stream>>>(x, xb, NNODES * 256 / 4);
    transpose_w<<<dim3((256 * 256 + 255) / 256), 256, 0, stream>>>(W1, W1t, 256, 256);
    transpose_w<<<dim3((256 * 128 + 255) / 256), 256, 0, stream>>>(W2, W2t, 256, 128);
    transpose_w<<<dim3((128 * 128 + 255) / 256), 256, 0, stream>>>(Wmu, Wht, 128, 128);
    transpose_w<<<dim3((128 * 128 + 255) / 256), 256, 0, stream>>>(Wlv, Wht + 128 * 128, 128, 128);
    concat_bias<<<1, 256, 0, stream>>>(bmu, blv, bcat);

    // conv1: xw1' = dinv .* (x @ W1)   [bf16]
    gemm_bt<256, 256, 0><<<dim3(MP / 128, 2), 256, 0, stream>>>(xb, W1t, xw1, nullptr, dinv, nullptr, MP);
    agg_phased<256, true><<<dim3(AGG_BLOCKS), 128, 0, stream>>>(xw1, csr, bb, dinv, b1, z1, E);

    // conv2: xw2' = dinv .* (z1 @ W2)  [bf16]
    gemm_bt<256, 128, 0><<<dim3(MP / 128, 1), 256, 0, stream>>>(z1, W2t, xw2, nullptr, dinv, nullptr, MP);
    agg_phased<128, false><<<dim3(AGG_BLOCKS), 128, 0, stream>>>(xw2, csr, bb, dinv, b2, z2, E);

    // fused heads: [mu | logvar] = z2 @ [Wmu Wlv] + [bmu blv], split-stored
    gemm_bt<128, 256, 1><<<dim3(MP / 128, 2), 256, 0, stream>>>(z2, Wht, nullptr, out, dinv, bcat, NNODES);
}

// Round 9
// 2677.968 us; speedup vs baseline: 1.3232x; 1.3033x over previous
//
#include <hip/hip_runtime.h>

typedef unsigned int uint;
typedef unsigned short ushort;

#define NNODES 100000
#define MP 100096   // 782 * 128
#define NP 100096
#define NB 32       // column buckets (phase slabs of 3125 cols)
#define RPW 49      // rows per wave in phased aggregation

typedef __attribute__((ext_vector_type(8))) short bf16x8;
typedef __attribute__((ext_vector_type(4))) float f32x4;
typedef __attribute__((ext_vector_type(2))) float f32x2;

__device__ __forceinline__ float b2f(uint u) {
    union { float f; uint i; } x; x.i = u << 16; return x.f;
}
__device__ __forceinline__ ushort f2b(float f) {
    uint u = __float_as_uint(f);
    u = (u + 0x7fffu + ((u >> 16) & 1u)) >> 16;
    return (ushort)u;
}

// bucket(c) = floor-ish(c / ~3125), consistent everywhere; c < 100000 -> 0..31
__device__ __forceinline__ int colbucket(int c) {
    return (int)(((uint)c * 671u) >> 21);
}

// ---------------- graph preprocessing (bucketed CSR) ----------------
// edge_index arrives as int32: rows = p[0:E], cols = p[E:2E]

__global__ void count_edges2(const int* __restrict__ rows, const int* __restrict__ cols,
                             int* __restrict__ cnt2, int E) {
    int i = blockIdx.x * 256 + threadIdx.x;
    if (i < E) {
        uint r = (uint)rows[i];
        uint c = (uint)cols[i];
        if (r < NNODES && c < NNODES)
            atomicAdd(&cnt2[(size_t)r * NB + colbucket((int)c)], 1);
    }
}

// per-row: deg, dinv, global row_start via wave-scan + one atomic per wave,
// per-bucket prefix -> bb[row][k] = (start, count); cursor2 seeded with start.
__global__ __launch_bounds__(256) void scan_rows(
        const int* __restrict__ cnt2, float* __restrict__ dinv,
        int2* __restrict__ bb, int* __restrict__ cursor2, int* __restrict__ gcur) {
    int row = blockIdx.x * 256 + threadIdx.x;
    int lane = threadIdx.x & 63;
    int c[NB];
    int deg = 0;
    if (row < NNODES) {
#pragma unroll
        for (int k = 0; k < NB; k += 4) {
            int4 v = *(const int4*)&cnt2[(size_t)row * NB + k];
            c[k] = v.x; c[k + 1] = v.y; c[k + 2] = v.z; c[k + 3] = v.w;
            deg += v.x + v.y + v.z + v.w;
        }
        dinv[row] = rsqrtf((float)(deg + 1));
    }
    int incl = deg;
#pragma unroll
    for (int off = 1; off < 64; off <<= 1) {
        int u = __shfl_up(incl, off, 64);
        if (lane >= off) incl += u;
    }
    int base = 0;
    if (lane == 63) base = atomicAdd(gcur, incl);
    base = __shfl(base, 63, 64);
    int p = base + incl - deg;
    if (row < NNODES) {
#pragma unroll
        for (int k = 0; k < NB; ++k) {
            bb[(size_t)row * NB + k] = make_int2(p, c[k]);
            cursor2[(size_t)row * NB + k] = p;
            p += c[k];
        }
    }
}

__global__ void fill_csr2(const int* __restrict__ rows, const int* __restrict__ cols,
                          int* __restrict__ cursor2, int* __restrict__ csr_col, int E) {
    int i = blockIdx.x * 256 + threadIdx.x;
    if (i < E) {
        uint r = (uint)rows[i];
        uint c = (uint)cols[i];
        if (r < NNODES && c < NNODES) {
            int pos = atomicAdd(&cursor2[(size_t)r * NB + colbucket((int)c)], 1);
            csr_col[pos] = (int)c;
        }
    }
}

// ---------------- dtype conversion ----------------

__global__ void convert_x(const float* __restrict__ X, ushort* __restrict__ Xb, int n4) {
    int i = blockIdx.x * 256 + threadIdx.x;
    if (i < n4) {
        float4 v = ((const float4*)X)[i];
        uint2 o;
        o.x = (uint)f2b(v.x) | ((uint)f2b(v.y) << 16);
        o.y = (uint)f2b(v.z) | ((uint)f2b(v.w) << 16);
        ((uint2*)Xb)[i] = o;
    }
}

__global__ void transpose_w(const float* __restrict__ W, ushort* __restrict__ Wt, int K, int Nout) {
    int i = blockIdx.x * 256 + threadIdx.x;
    if (i < K * Nout) {
        int k = i / Nout, n = i % Nout;
        Wt[(size_t)n * K + k] = f2b(W[i]);
    }
}

__global__ void concat_bias(const float* __restrict__ a, const float* __restrict__ b,
                            float* __restrict__ o) {
    int i = threadIdx.x;           // 256 threads
    o[i] = (i < 128) ? a[i] : b[i - 128];
}

// ---------------- GEMM: C = A (Mp x K) * Bt^T (Bt is Nout x K), bf16 MFMA ----------------
// EPI 0: C[m][n] = dinv[m] * acc  -> bf16 Cb
// EPI 1: C[m][n] = acc + bias[n]  -> fp32, split-store

template<int KDIM, int NOUT, int EPI>
__global__ __launch_bounds__(256, 2) void gemm_bt(
        const ushort* __restrict__ A, const ushort* __restrict__ Bt,
        ushort* __restrict__ Cb, float* __restrict__ Cf,
        const float* __restrict__ dinv, const float* __restrict__ bias, int Mvalid) {
    __shared__ __align__(16) ushort Alds[128][72];
    __shared__ __align__(16) ushort Blds[128][72];
    __shared__ float dlds[128];

    const int tid = threadIdx.x;
    const int bm0 = blockIdx.x * 128;
    const int bn0 = blockIdx.y * 128;
    const int w = tid >> 6, lane = tid & 63;
    const int wm = (w >> 1) * 64, wn = (w & 1) * 64;
    const int lm = lane & 15, lq = lane >> 4;

    f32x4 acc[4][4] = {};
    if (EPI == 0 && tid < 128) dlds[tid] = dinv[bm0 + tid];

    const int sr = tid >> 3;        // 0..31
    const int sc = (tid & 7) * 8;   // bf16 col 0..56

    for (int k0 = 0; k0 < KDIM; k0 += 64) {
        uint4 ar[4], br[4];
#pragma unroll
        for (int i = 0; i < 4; ++i) {
            int r = sr + i * 32;
            ar[i] = *(const uint4*)&A[(size_t)(bm0 + r) * KDIM + k0 + sc];
            br[i] = *(const uint4*)&Bt[(size_t)(bn0 + r) * KDIM + k0 + sc];
        }
        __syncthreads();
#pragma unroll
        for (int i = 0; i < 4; ++i) {
            int r = sr + i * 32;
            *(uint4*)&Alds[r][sc] = ar[i];
            *(uint4*)&Blds[r][sc] = br[i];
        }
        __syncthreads();
#pragma unroll
        for (int kk = 0; kk < 64; kk += 32) {
            bf16x8 af[4], bfr[4];
#pragma unroll
            for (int t = 0; t < 4; ++t) af[t]  = *(const bf16x8*)&Alds[wm + t * 16 + lm][kk + lq * 8];
#pragma unroll
            for (int t = 0; t < 4; ++t) bfr[t] = *(const bf16x8*)&Blds[wn + t * 16 + lm][kk + lq * 8];
#pragma unroll
            for (int tm = 0; tm < 4; ++tm)
#pragma unroll
                for (int tn = 0; tn < 4; ++tn)
                    acc[tm][tn] = __builtin_amdgcn_mfma_f32_16x16x32_bf16(
                        af[tm], bfr[tn], acc[tm][tn], 0, 0, 0);
        }
    }

    // epilogue: C/D layout col = lane&15, row = (lane>>4)*4 + reg  [m89/m91]
#pragma unroll
    for (int tm = 0; tm < 4; ++tm) {
#pragma unroll
        for (int tn = 0; tn < 4; ++tn) {
#pragma unroll
            for (int r = 0; r < 4; ++r) {
                int lr = wm + tm * 16 + lq * 4 + r;
                int gr = bm0 + lr;
                int gc = bn0 + wn + tn * 16 + lm;
                float v = acc[tm][tn][r];
                if (EPI == 0) {
                    v *= dlds[lr];
                    Cb[(size_t)gr * NOUT + gc] = f2b(v);
                } else {
                    v += bias[gc];
                    if (gr < Mvalid) {
                        size_t off = (gc < 128)
                            ? ((size_t)gr * 128 + gc)
                            : ((size_t)NNODES * 128 + (size_t)gr * 128 + (gc - 128));
                        Cf[off] = v;
                    }
                }
            }
        }
    }
}

// ---------------- phased aggregation (feature-split waves) ----------------
// out[r] = act(dinv[r]*(sum_{c in N(r)} xw'[c] + xw'[r]) + b)   (xw' rows pre-scaled by dinv)
//
// R4: array accs -> scratch (SROA fail). R5: named 49xf32x4 accs STILL spilled --
// VGPR=128 despite a 256 budget: the backend's occupancy heuristic targets 4 waves/SIMD
// (128 regs) and spills to fit. Fix: make per-wave state fit 128 regs BY CONSTRUCTION:
// each wave holds 49 rows x 2 f32 = 98 acc regs (+~25 temps ~= 125 < 128).
//   F=256: block's 2 waves cover the SAME 49 rows, DIFFERENT 128-feature halves.
//   F=128: block's 2 waves cover DIFFERENT 49-row sets, full feature width.
// 4 waves/SIMD -> 4096 resident waves >= grid waves -> single lockstep generation.
// All waves sweep NB=32 column buckets in the same order: instantaneous gather working
// set ~1-2 slabs (1.6-3.2 MB) -> per-XCD L2 resident. Branchless passes A (edge 0),
// B (edge 1), C (rare 2+); next-phase cols prefetched; inactive rows gather a hot
// in-slab dummy row with FMA*0. sched_barrier every 8 rows caps in-flight gathers.

#define ROWS49(X) \
    X(0) X(1) X(2) X(3) X(4) X(5) X(6) X(7) X(8) X(9) \
    X(10) X(11) X(12) X(13) X(14) X(15) X(16) X(17) X(18) X(19) \
    X(20) X(21) X(22) X(23) X(24) X(25) X(26) X(27) X(28) X(29) \
    X(30) X(31) X(32) X(33) X(34) X(35) X(36) X(37) X(38) X(39) \
    X(40) X(41) X(42) X(43) X(44) X(45) X(46) X(47) X(48)

// fence every 8 rows: caps gathers the pre-RA scheduler can hoist (pressure control)
#define SBAR __builtin_amdgcn_sched_barrier(0);
#define ROWS49G(X) \
    X(0) X(1) X(2) X(3) X(4) X(5) X(6) X(7) SBAR \
    X(8) X(9) X(10) X(11) X(12) X(13) X(14) X(15) SBAR \
    X(16) X(17) X(18) X(19) X(20) X(21) X(22) X(23) SBAR \
    X(24) X(25) X(26) X(27) X(28) X(29) X(30) X(31) SBAR \
    X(32) X(33) X(34) X(35) X(36) X(37) X(38) X(39) SBAR \
    X(40) X(41) X(42) X(43) X(44) X(45) X(46) X(47) SBAR \
    X(48)

template<int F, bool RELU>
__global__ __launch_bounds__(128) void agg_phased(
        const ushort* __restrict__ xw, const int* __restrict__ csr,
        const int2* __restrict__ bb, const float* __restrict__ dinv,
        const float* __restrict__ bias, ushort* __restrict__ out, int E) {
    const int lane = threadIdx.x & 63;
    const int w = threadIdx.x >> 6;
    // F=256: waves share rows, split features; F=128: waves split rows, full features
    const int row0 = (F == 256 ? (int)blockIdx.x : (int)blockIdx.x * 2 + w) * RPW;
    const int fo = (F == 256 ? (w * 64 + lane) : lane) * 2;   // ushort col offset
    const int myrow = row0 + lane;
    const bool rv = (lane < RPW) && (myrow < NNODES);
    const float dvl = rv ? dinv[myrow] : 0.f;
    const int Emax = E - 1;
    const ushort* tb = xw + fo;              // per-lane feature-pair base

    // per-row gather-accumulate: 1 uint load (2 bf16) + 2 fmaf
#define GACC(cc, m, ar) do { \
        uint v_ = *(const uint*)(tb + (size_t)(cc) * F); \
        ar[0] = fmaf((m), b2f(v_ & 0xffffu), ar[0]); \
        ar[1] = fmaf((m), b2f(v_ >> 16),     ar[1]); } while (0)

    // 49 named f32x2 accumulators (registers by construction: 98 VGPRs)
#define DECLA(r) f32x2 a##r = {};
    ROWS49(DECLA)
#undef DECLA

    // self contributions (phase-independent; row0+r < MP always so loads are safe;
    // garbage rows >= NNODES only pollute accumulators that are never stored)
#define SELFA(r) GACC(row0 + r, 1.f, a##r);
    ROWS49G(SELFA)
#undef SELFA

    // phase-0 metadata + first/second column prefetch (lane l holds row row0+l's bucket)
    int2 sn = rv ? bb[(size_t)myrow * NB + 0] : make_int2(0, 0);
    int i0 = (sn.x < Emax) ? sn.x : Emax;
    int i1 = (sn.x + 1 < Emax) ? sn.x + 1 : Emax;
    int c0v = csr[i0];
    int c1v = csr[i1];

    for (int b = 0; b < NB; ++b) {
        const int bn = (b + 1 < NB) ? b + 1 : b;
        int2 snn = rv ? bb[(size_t)myrow * NB + bn] : make_int2(0, 0);
        const int dummyc = b * 3125;         // hot in-slab row; finite; < NNODES

        // pass A: first edge of each bucket (branchless straight-line)
#define PASSA(r) { int n = __shfl(sn.y, r, 64); int cc = __shfl(c0v, r, 64); \
                   float m = (n >= 1) ? 1.f : 0.f; cc = (n >= 1) ? cc : dummyc; \
                   GACC(cc, m, a##r); }
        ROWS49G(PASSA)
#undef PASSA

        // next-phase column prefetch (overlaps with pass B)
        int j0 = (snn.x < Emax) ? snn.x : Emax;
        int j1 = (snn.x + 1 < Emax) ? snn.x + 1 : Emax;
        int c0n = csr[j0];
        int c1n = csr[j1];

        // pass B: second edge (branchless)
#define PASSB(r) { int n = __shfl(sn.y, r, 64); int cc = __shfl(c1v, r, 64); \
                   float m = (n >= 2) ? 1.f : 0.f; cc = (n >= 2) ? cc : dummyc; \
                   GACC(cc, m, a##r); }
        ROWS49G(PASSB)
#undef PASSB

        // pass C: remaining edges (P(n>=3) ~ 8%, csr line already warm)
#define PASSC(r) { int n = __shfl(sn.y, r, 64); \
                   if (n >= 3) { int s = __shfl(sn.x, r, 64); int e = s + n; \
                                 for (int i = s + 2; i < e; ++i) GACC(csr[i], 1.f, a##r); } }
        ROWS49G(PASSC)
#undef PASSC

        sn = snn; c0v = c0n; c1v = c1n;
        __syncthreads();                     // keep the block's 2 waves phase-aligned
    }

    // epilogue: scale by dinv[row], add bias, optional relu, bf16 store
    // (plain stores: z1/z2 are re-read by the next GEMM/aggregation, keep cached)
    float2 bv = *(const float2*)&bias[fo];
#define EPIL(r) { int row = row0 + r; \
    if (row < NNODES) { \
        float d = __shfl(dvl, r, 64); \
        float r0 = a##r[0] * d + bv.x; \
        float r1 = a##r[1] * d + bv.y; \
        if (RELU) { r0 = fmaxf(r0, 0.f); r1 = fmaxf(r1, 0.f); } \
        *(uint*)(out + (size_t)row * F + fo) = (uint)f2b(r0) | ((uint)f2b(r1) << 16); } }
    ROWS49(EPIL)
#undef EPIL
#undef GACC
}

// ---------------- launch ----------------

extern "C" void kernel_launch(void* const* d_in, const int* in_sizes, int n_in,
                              void* d_out, int out_size, void* d_ws, size_t ws_size,
                              hipStream_t stream) {
    (void)n_in; (void)out_size; (void)ws_size;
    const float* x   = (const float*)d_in[0];
    const int*   ei  = (const int*)d_in[1];   // int64 in reference -> int32 from harness
    const float* W1  = (const float*)d_in[2];
    const float* b1  = (const float*)d_in[3];
    const float* W2  = (const float*)d_in[4];
    const float* b2  = (const float*)d_in[5];
    const float* Wmu = (const float*)d_in[6];
    const float* bmu = (const float*)d_in[7];
    const float* Wlv = (const float*)d_in[8];
    const float* blv = (const float*)d_in[9];
    float* out = (float*)d_out;

    const int E = in_sizes[1] / 2;
    const int* rows = ei;
    const int* cols = ei + E;

    char* ws = (char*)d_ws;
    size_t o = 0;
    int2*  bb   = (int2*)(ws + o);  o += (size_t)NNODES * NB * sizeof(int2);  // 25.6 MB
    float* dinv = (float*)(ws + o); o += (size_t)NP * 4;
    int*   gcur = (int*)(ws + o);   o += 256;
    float* bcat = (float*)(ws + o); o += 1024;
    ushort* W1t = (ushort*)(ws + o); o += 256 * 256 * 2;
    ushort* W2t = (ushort*)(ws + o); o += 256 * 128 * 2;
    ushort* Wht = (ushort*)(ws + o); o += 256 * 128 * 2;  // [Wmu^T ; Wlv^T]
    int*   csr  = (int*)(ws + o);   o += (size_t)E * 4;
    o = (o + 4095) & ~(size_t)4095;
    ushort* bufA = (ushort*)(ws + o); o += (size_t)MP * 256 * 2;
    ushort* bufB = (ushort*)(ws + o); o += (size_t)MP * 256 * 2;

    // cnt2/cursor2 alias the head of bufB: dead before gemm1 writes xw1 there.
    int* cnt2    = (int*)bufB;
    int* cursor2 = (int*)((char*)bufB + (size_t)NNODES * NB * 4);

    // buffer lifetimes: bufA = xb -> z1 -> z2 ; bufB = (cnt2|cursor2) -> xw1 -> xw2
    ushort* xb  = bufA;
    ushort* xw1 = bufB;
    ushort* z1  = bufA;
    ushort* xw2 = bufB;
    ushort* z2  = bufA;

    (void)hipMemsetAsync(cnt2, 0, (size_t)NNODES * NB * 4, stream);
    (void)hipMemsetAsync(gcur, 0, 4, stream);

    count_edges2<<<dim3((E + 255) / 256), 256, 0, stream>>>(rows, cols, cnt2, E);
    scan_rows<<<dim3((NNODES + 255) / 256), 256, 0, stream>>>(cnt2, dinv, bb, cursor2, gcur);
    fill_csr2<<<dim3((E + 255) / 256), 256, 0, stream>>>(rows, cols, cursor2, csr, E);

    convert_x<<<dim3((NNODES * 256 / 4 + 255) / 256), 256, 0, stream>>>(x, xb, NNODES * 256 / 4);
    transpose_w<<<dim3((256 * 256 + 255) / 256), 256, 0, stream>>>(W1, W1t, 256, 256);
    transpose_w<<<dim3((256 * 128 + 255) / 256), 256, 0, stream>>>(W2, W2t, 256, 128);
    transpose_w<<<dim3((128 * 128 + 255) / 256), 256, 0, stream>>>(Wmu, Wht, 128, 128);
    transpose_w<<<dim3((128 * 128 + 255) / 256), 256, 0, stream>>>(Wlv, Wht + 128 * 128, 128, 128);
    concat_bias<<<1, 256, 0, stream>>>(bmu, blv, bcat);

    // grids: F=256 -> one 49-row set per block (2 waves split features) -> 2041 blocks
    //        F=128 -> two 49-row sets per block (2 waves split rows)    -> 1021 blocks
    const int G256 = (NNODES + RPW - 1) / RPW;            // 2041
    const int G128 = (NNODES + 2 * RPW - 1) / (2 * RPW);  // 1021

    // conv1: xw1' = dinv .* (x @ W1)   [bf16]
    gemm_bt<256, 256, 0><<<dim3(MP / 128, 2), 256, 0, stream>>>(xb, W1t, xw1, nullptr, dinv, nullptr, MP);
    agg_phased<256, true><<<dim3(G256), 128, 0, stream>>>(xw1, csr, bb, dinv, b1, z1, E);

    // conv2: xw2' = dinv .* (z1 @ W2)  [bf16]
    gemm_bt<256, 128, 0><<<dim3(MP / 128, 1), 256, 0, stream>>>(z1, W2t, xw2, nullptr, dinv, nullptr, MP);
    agg_phased<128, false><<<dim3(G128), 128, 0, stream>>>(xw2, csr, bb, dinv, b2, z2, E);

    // fused heads: [mu | logvar] = z2 @ [Wmu Wlv] + [bmu blv], split-stored
    gemm_bt<128, 256, 1><<<dim3(MP / 128, 2), 256, 0, stream>>>(z2, Wht, nullptr, out, dinv, bcat, NNODES);
}

// Round 14
// 1024.193 us; speedup vs baseline: 3.4599x; 2.6147x over previous
//
#include <hip/hip_runtime.h>

typedef unsigned int uint;
typedef unsigned short ushort;

#define NNODES 100000
#define MP 100096   // 782 * 128
#define NP 100096

typedef __attribute__((ext_vector_type(8))) short bf16x8;
typedef __attribute__((ext_vector_type(4))) float f32x4;

__device__ __forceinline__ float b2f(uint u) {
    union { float f; uint i; } x; x.i = u << 16; return x.f;
}
__device__ __forceinline__ ushort f2b(float f) {
    uint u = __float_as_uint(f);
    u = (u + 0x7fffu + ((u >> 16) & 1u)) >> 16;
    return (ushort)u;
}

// ---------------- graph preprocessing ----------------
// edge_index arrives as int32 (harness converts integer inputs to int): rows = p[0:E], cols = p[E:2E]

__global__ void count_edges(const int* __restrict__ rows, int* __restrict__ cnt, int E) {
    int i = blockIdx.x * 256 + threadIdx.x;
    if (i < E) {
        uint r = (uint)rows[i];
        if (r < NNODES) atomicAdd(&cnt[r], 1);
    }
}

// dinv[i] = rsqrt(cnt[i]+1); row_start via wave-scan + one atomic per wave
__global__ __launch_bounds__(256) void dinv_rowstart(
        const int* __restrict__ cnt, float* __restrict__ dinv,
        int* __restrict__ row_start, int* __restrict__ gcur) {
    int i = blockIdx.x * 256 + threadIdx.x;
    int lane = threadIdx.x & 63;
    int c = (i < NNODES) ? cnt[i] : 0;
    if (i < NNODES) dinv[i] = rsqrtf((float)(c + 1));
    int incl = c;
#pragma unroll
    for (int off = 1; off < 64; off <<= 1) {
        int u = __shfl_up(incl, off, 64);
        if (lane >= off) incl += u;
    }
    int base = 0;
    if (lane == 63) base = atomicAdd(gcur, incl);
    base = __shfl(base, 63, 64);
    if (i < NNODES) row_start[i] = base + incl - c;
}

__global__ void fill_csr(const int* __restrict__ rows, const int* __restrict__ cols,
                         const int* __restrict__ row_start, int* __restrict__ cursor,
                         int* __restrict__ csr_col, int E) {
    int i = blockIdx.x * 256 + threadIdx.x;
    if (i < E) {
        uint r = (uint)rows[i];
        uint c = (uint)cols[i];
        if (r < NNODES && c < NNODES) {
            int slot = atomicAdd(&cursor[r], 1);
            csr_col[row_start[r] + slot] = (int)c;
        }
    }
}

// ---------------- dtype conversion ----------------

__global__ void convert_x(const float* __restrict__ X, ushort* __restrict__ Xb, int n4) {
    int i = blockIdx.x * 256 + threadIdx.x;
    if (i < n4) {
        float4 v = ((const float4*)X)[i];
        uint2 o;
        o.x = (uint)f2b(v.x) | ((uint)f2b(v.y) << 16);
        o.y = (uint)f2b(v.z) | ((uint)f2b(v.w) << 16);
        ((uint2*)Xb)[i] = o;
    }
}

__global__ void transpose_w(const float* __restrict__ W, ushort* __restrict__ Wt, int K, int Nout) {
    int i = blockIdx.x * 256 + threadIdx.x;
    if (i < K * Nout) {
        int k = i / Nout, n = i % Nout;
        Wt[(size_t)n * K + k] = f2b(W[i]);
    }
}

__global__ void concat_bias(const float* __restrict__ a, const float* __restrict__ b,
                            float* __restrict__ o) {
    int i = threadIdx.x;           // 256 threads
    o[i] = (i < 128) ? a[i] : b[i - 128];
}

// ---------------- GEMM: C = A (Mp x K) * Bt^T (Bt is Nout x K), bf16 MFMA ----------------
// EPI 0: C[m][n] = dinv[m] * acc  -> bf16 Cb
// EPI 1: C[m][n] = acc + bias[n]  -> fp32, split-store: cols 0-127 -> Cf[m][c],
//        cols 128-255 -> Cf[NNODES*128 + m][c-128]; only m < Mvalid

template<int KDIM, int NOUT, int EPI>
__global__ __launch_bounds__(256, 2) void gemm_bt(
        const ushort* __restrict__ A, const ushort* __restrict__ Bt,
        ushort* __restrict__ Cb, float* __restrict__ Cf,
        const float* __restrict__ dinv, const float* __restrict__ bias, int Mvalid) {
    __shared__ __align__(16) ushort Alds[128][72];
    __shared__ __align__(16) ushort Blds[128][72];
    __shared__ float dlds[128];

    const int tid = threadIdx.x;
    const int bm0 = blockIdx.x * 128;
    const int bn0 = blockIdx.y * 128;
    const int w = tid >> 6, lane = tid & 63;
    const int wm = (w >> 1) * 64, wn = (w & 1) * 64;
    const int lm = lane & 15, lq = lane >> 4;

    f32x4 acc[4][4] = {};
    if (EPI == 0 && tid < 128) dlds[tid] = dinv[bm0 + tid];

    const int sr = tid >> 3;        // 0..31
    const int sc = (tid & 7) * 8;   // bf16 col 0..56

    for (int k0 = 0; k0 < KDIM; k0 += 64) {
        uint4 ar[4], br[4];
#pragma unroll
        for (int i = 0; i < 4; ++i) {
            int r = sr + i * 32;
            ar[i] = *(const uint4*)&A[(size_t)(bm0 + r) * KDIM + k0 + sc];
            br[i] = *(const uint4*)&Bt[(size_t)(bn0 + r) * KDIM + k0 + sc];
        }
        __syncthreads();
#pragma unroll
        for (int i = 0; i < 4; ++i) {
            int r = sr + i * 32;
            *(uint4*)&Alds[r][sc] = ar[i];
            *(uint4*)&Blds[r][sc] = br[i];
        }
        __syncthreads();
#pragma unroll
        for (int kk = 0; kk < 64; kk += 32) {
            bf16x8 af[4], bfr[4];
#pragma unroll
            for (int t = 0; t < 4; ++t) af[t]  = *(const bf16x8*)&Alds[wm + t * 16 + lm][kk + lq * 8];
#pragma unroll
            for (int t = 0; t < 4; ++t) bfr[t] = *(const bf16x8*)&Blds[wn + t * 16 + lm][kk + lq * 8];
#pragma unroll
            for (int tm = 0; tm < 4; ++tm)
#pragma unroll
                for (int tn = 0; tn < 4; ++tn)
                    acc[tm][tn] = __builtin_amdgcn_mfma_f32_16x16x32_bf16(
                        af[tm], bfr[tn], acc[tm][tn], 0, 0, 0);
        }
    }

    // epilogue: C/D layout col = lane&15, row = (lane>>4)*4 + reg  [m89/m91]
#pragma unroll
    for (int tm = 0; tm < 4; ++tm) {
#pragma unroll
        for (int tn = 0; tn < 4; ++tn) {
#pragma unroll
            for (int r = 0; r < 4; ++r) {
                int lr = wm + tm * 16 + lq * 4 + r;
                int gr = bm0 + lr;
                int gc = bn0 + wn + tn * 16 + lm;
                float v = acc[tm][tn][r];
                if (EPI == 0) {
                    v *= dlds[lr];
                    Cb[(size_t)gr * NOUT + gc] = f2b(v);
                } else {
                    v += bias[gc];
                    if (gr < Mvalid) {
                        size_t off = (gc < 128)
                            ? ((size_t)gr * 128 + gc)
                            : ((size_t)NNODES * 128 + (size_t)gr * 128 + (gc - 128));
                        Cf[off] = v;
                    }
                }
            }
        }
    }
}

// ---------------- aggregation: out[r] = act(dinv[r]*(sum_{c in N(r)} xw'[c] + xw'[r]) + b) ----------------
// xw' rows are pre-scaled by their own dinv in the GEMM epilogue.
// One wave per row. R9 evidence: F=128 agg took the SAME 220 us as F=256 at half the
// gather bytes -> the 8-deep pipeline was latency/issue-bound, not BW-bound.
// This round: deepen to 16 independent gathers in flight (then 8, then scalar tail).
// (The phased/bucketed rewrite of R4-R9 is dead: locality worked (FETCH 775->560 MB)
// but register-resident accumulators forced ~4 waves/CU and its shfl+dummy-slot
// structure cost 295 us of pure VALU time -- worse than this kernel's total.)

template<int F, bool RELU>
__global__ __launch_bounds__(256) void aggregate(
        const ushort* __restrict__ xw, const int* __restrict__ csr_col,
        const int* __restrict__ row_start, const int* __restrict__ cnt,
        const float* __restrict__ dinv, const float* __restrict__ bias,
        ushort* __restrict__ out) {
    const int row = blockIdx.x * 4 + (threadIdx.x >> 6);
    if (row >= NNODES) return;
    const int lane = threadIdx.x & 63;
    const int s = row_start[row];
    const int e = s + cnt[row];
    const float d = dinv[row];

    if (F == 256) {
        const int f0 = lane * 4;
        const ushort* base = xw + f0;
        uint2 sv = *(const uint2*)(base + (size_t)row * F);
        float a0 = b2f(sv.x & 0xffffu), a1 = b2f(sv.x >> 16);
        float a2 = b2f(sv.y & 0xffffu), a3 = b2f(sv.y >> 16);
        int i = s;
        for (; i + 16 <= e; i += 16) {
            int c[16];
            uint2 v[16];
#pragma unroll
            for (int j = 0; j < 16; ++j) c[j] = csr_col[i + j];
#pragma unroll
            for (int j = 0; j < 16; ++j) v[j] = *(const uint2*)(base + (size_t)c[j] * F);
#pragma unroll
            for (int j = 0; j < 16; ++j) {
                a0 += b2f(v[j].x & 0xffffu); a1 += b2f(v[j].x >> 16);
                a2 += b2f(v[j].y & 0xffffu); a3 += b2f(v[j].y >> 16);
            }
        }
        for (; i + 8 <= e; i += 8) {
            int c[8];
            uint2 v[8];
#pragma unroll
            for (int j = 0; j < 8; ++j) c[j] = csr_col[i + j];
#pragma unroll
            for (int j = 0; j < 8; ++j) v[j] = *(const uint2*)(base + (size_t)c[j] * F);
#pragma unroll
            for (int j = 0; j < 8; ++j) {
                a0 += b2f(v[j].x & 0xffffu); a1 += b2f(v[j].x >> 16);
                a2 += b2f(v[j].y & 0xffffu); a3 += b2f(v[j].y >> 16);
            }
        }
        for (; i < e; ++i) {
            uint2 v = *(const uint2*)(base + (size_t)csr_col[i] * F);
            a0 += b2f(v.x & 0xffffu); a1 += b2f(v.x >> 16);
            a2 += b2f(v.y & 0xffffu); a3 += b2f(v.y >> 16);
        }
        float r0 = a0 * d + bias[f0 + 0];
        float r1 = a1 * d + bias[f0 + 1];
        float r2 = a2 * d + bias[f0 + 2];
        float r3 = a3 * d + bias[f0 + 3];
        if (RELU) {
            r0 = fmaxf(r0, 0.f); r1 = fmaxf(r1, 0.f);
            r2 = fmaxf(r2, 0.f); r3 = fmaxf(r3, 0.f);
        }
        uint2 o;
        o.x = (uint)f2b(r0) | ((uint)f2b(r1) << 16);
        o.y = (uint)f2b(r2) | ((uint)f2b(r3) << 16);
        *(uint2*)(out + (size_t)row * F + f0) = o;
    } else {
        const int f0 = lane * 2;
        const ushort* base = xw + f0;
        uint sv = *(const uint*)(base + (size_t)row * F);
        float a0 = b2f(sv & 0xffffu), a1 = b2f(sv >> 16);
        int i = s;
        for (; i + 16 <= e; i += 16) {
            int c[16];
            uint v[16];
#pragma unroll
            for (int j = 0; j < 16; ++j) c[j] = csr_col[i + j];
#pragma unroll
            for (int j = 0; j < 16; ++j) v[j] = *(const uint*)(base + (size_t)c[j] * F);
#pragma unroll
            for (int j = 0; j < 16; ++j) {
                a0 += b2f(v[j] & 0xffffu); a1 += b2f(v[j] >> 16);
            }
        }
        for (; i + 8 <= e; i += 8) {
            int c[8];
            uint v[8];
#pragma unroll
            for (int j = 0; j < 8; ++j) c[j] = csr_col[i + j];
#pragma unroll
            for (int j = 0; j < 8; ++j) v[j] = *(const uint*)(base + (size_t)c[j] * F);
#pragma unroll
            for (int j = 0; j < 8; ++j) {
                a0 += b2f(v[j] & 0xffffu); a1 += b2f(v[j] >> 16);
            }
        }
        for (; i < e; ++i) {
            uint v = *(const uint*)(base + (size_t)csr_col[i] * F);
            a0 += b2f(v & 0xffffu); a1 += b2f(v >> 16);
        }
        float r0 = a0 * d + bias[f0 + 0];
        float r1 = a1 * d + bias[f0 + 1];
        if (RELU) { r0 = fmaxf(r0, 0.f); r1 = fmaxf(r1, 0.f); }
        *(uint*)(out + (size_t)row * F + f0) = (uint)f2b(r0) | ((uint)f2b(r1) << 16);
    }
}

// ---------------- launch ----------------

extern "C" void kernel_launch(void* const* d_in, const int* in_sizes, int n_in,
                              void* d_out, int out_size, void* d_ws, size_t ws_size,
                              hipStream_t stream) {
    (void)n_in; (void)out_size; (void)ws_size;
    const float* x   = (const float*)d_in[0];
    const int*   ei  = (const int*)d_in[1];   // int64 in reference -> int32 from harness
    const float* W1  = (const float*)d_in[2];
    const float* b1  = (const float*)d_in[3];
    const float* W2  = (const float*)d_in[4];
    const float* b2  = (const float*)d_in[5];
    const float* Wmu = (const float*)d_in[6];
    const float* bmu = (const float*)d_in[7];
    const float* Wlv = (const float*)d_in[8];
    const float* blv = (const float*)d_in[9];
    float* out = (float*)d_out;

    const int E = in_sizes[1] / 2;
    const int* rows = ei;
    const int* cols = ei + E;

    char* ws = (char*)d_ws;
    size_t o = 0;
    int*   cnt       = (int*)(ws + o); o += (size_t)NP * 4;
    int*   cursor    = (int*)(ws + o); o += (size_t)NP * 4;
    int*   gcur      = (int*)(ws + o); o += 256;
    const size_t ZBYTES = o;           // zero cnt + cursor + gcur
    int*   row_start = (int*)(ws + o); o += (size_t)NP * 4;
    float* dinv      = (float*)(ws + o); o += (size_t)NP * 4;
    float* bcat      = (float*)(ws + o); o += 256 * 4;
    int*   csr       = (int*)(ws + o); o += (size_t)E * 4;
    ushort* W1t      = (ushort*)(ws + o); o += 256 * 256 * 2;
    ushort* W2t      = (ushort*)(ws + o); o += 256 * 128 * 2;
    ushort* Wht      = (ushort*)(ws + o); o += 256 * 128 * 2;  // [Wmu^T ; Wlv^T] rows 0-127 / 128-255
    o = (o + 4095) & ~(size_t)4095;
    ushort* bufA = (ushort*)(ws + o); o += (size_t)MP * 256 * 2;
    ushort* bufB = (ushort*)(ws + o); o += (size_t)MP * 256 * 2;

    // buffer lifetimes: bufA = xb -> z1 -> z2 ; bufB = xw1 -> xw2
    ushort* xb  = bufA;
    ushort* xw1 = bufB;
    ushort* z1  = bufA;
    ushort* xw2 = bufB;
    ushort* z2  = bufA;

    (void)hipMemsetAsync(d_ws, 0, ZBYTES, stream);

    count_edges<<<dim3((E + 255) / 256), 256, 0, stream>>>(rows, cnt, E);
    dinv_rowstart<<<dim3((NNODES + 255) / 256), 256, 0, stream>>>(cnt, dinv, row_start, gcur);
    fill_csr<<<dim3((E + 255) / 256), 256, 0, stream>>>(rows, cols, row_start, cursor, csr, E);

    convert_x<<<dim3((NNODES * 256 / 4 + 255) / 256), 256, 0, stream>>>(x, xb, NNODES * 256 / 4);
    transpose_w<<<dim3((256 * 256 + 255) / 256), 256, 0, stream>>>(W1, W1t, 256, 256);
    transpose_w<<<dim3((256 * 128 + 255) / 256), 256, 0, stream>>>(W2, W2t, 256, 128);
    transpose_w<<<dim3((128 * 128 + 255) / 256), 256, 0, stream>>>(Wmu, Wht, 128, 128);
    transpose_w<<<dim3((128 * 128 + 255) / 256), 256, 0, stream>>>(Wlv, Wht + 128 * 128, 128, 128);
    concat_bias<<<1, 256, 0, stream>>>(bmu, blv, bcat);

    // conv1: xw1' = dinv .* (x @ W1)   [bf16]
    gemm_bt<256, 256, 0><<<dim3(MP / 128, 2), 256, 0, stream>>>(xb, W1t, xw1, nullptr, dinv, nullptr, MP);
    aggregate<256, true><<<dim3(NNODES / 4), 256, 0, stream>>>(xw1, csr, row_start, cnt, dinv, b1, z1);

    // conv2: xw2' = dinv .* (z1 @ W2)  [bf16]
    gemm_bt<256, 128, 0><<<dim3(MP / 128, 1), 256, 0, stream>>>(z1, W2t, xw2, nullptr, dinv, nullptr, MP);
    aggregate<128, false><<<dim3(NNODES / 4), 256, 0, stream>>>(xw2, csr, row_start, cnt, dinv, b2, z2);

    // fused heads: [mu | logvar] = z2 @ [Wmu Wlv] + [bmu blv], split-stored
    gemm_bt<128, 256, 1><<<dim3(MP / 128, 2), 256, 0, stream>>>(z2, Wht, nullptr, out, dinv, bcat, NNODES);
}